// Round 15
// baseline (696.605 us; speedup 1.0000x reference)
//
#include <hip/hip_runtime.h>
#include <hip/hip_fp16.h>
#include <hip/hip_cooperative_groups.h>

namespace cg = cooperative_groups;

// DGCF single-layer, 2 routing iters (MI355X). fp32 in / fp32 out.
// R14 post-mortem: outk flat again (77us) after halving math -> not issue
// bound; ~80us of the 308 wall is unaccounted -> dispatch-boundary theory.
// R15: CSR build (zero+count+scan+scan_add+scatter||prep) merged into ONE
// cooperative kernel with grid.sync() phases -> 9 dispatches down to 4.
// fused_attn / sm_dcol_y1 / outk byte-identical to R14 (passing, absmax 9.8e-4).

#define NUSERS 30000
#define NN     60000
#define EE     800000
#define SL     ((size_t)NN * 16)        // Y1s slice elements
#define SLY    ((size_t)(NN + 1) * 32)  // YT slice elements (+ zero row)
#define SCAN_B ((NN + 255) / 256)       // 235 data-carrying scan blocks
#define COOP_B 1024                     // cooperative grid (co-resident: 4 blk/CU)
#define COOP_WAVES (COOP_B * 4)

__device__ __forceinline__ float getX(const float* __restrict__ Gu,
                                      const float* __restrict__ Gi,
                                      int n, int c) {
    return (n < NUSERS) ? Gu[n * 64 + c] : Gi[(n - NUSERS) * 64 + c];
}

__device__ __forceinline__ int clampN(int n) {
    return ((unsigned)n < (unsigned)NN) ? n : 0;
}

__device__ __forceinline__ __half2 shfl_xor_h2(__half2 x, int m) {
    int xi = __builtin_bit_cast(int, x);
    xi = __shfl_xor(xi, m, 64);
    return __builtin_bit_cast(__half2, xi);
}

// Pinned-block index decode: blockIdx b -> intent i (XCD pair), node n.
__device__ __forceinline__ int pinnedNode(int b, int tid, int* i) {
    int xcd = b & 7;
    *i = xcd >> 1;
    int g = (b >> 3) * 2 + (xcd & 1);          // node-group in [0,15000)
    return g * 4 + (tid >> 6);
}

// ---- cooperative CSR build + YT prep (5 former dispatches in one) ----
__global__ void csr_build(const int* __restrict__ eh, const int* __restrict__ et,
                          int* __restrict__ deg0, int* __restrict__ cursor,
                          int* __restrict__ offsets, int* __restrict__ bsum,
                          int* __restrict__ csr_tail,
                          const float* __restrict__ Gu, const float* __restrict__ Gi,
                          __half* __restrict__ YT) {
    cg::grid_group grid = cg::this_grid();
    const int tid  = blockIdx.x * 256 + threadIdx.x;   // 0 .. 262143
    const int lane = threadIdx.x & 63;
    const int w    = threadIdx.x >> 6;
    __shared__ int wsum[4];
    __shared__ int bpre;

    // phase 0: zero deg0 + cursor
    if (tid < NN) { deg0[tid] = 0; cursor[tid] = 0; }
    grid.sync();

    // phase 1: degree count (int4; EE/4 = 200000 <= thread count, one shot)
    if (tid < EE / 4) {
        int4 h = ((const int4*)eh)[tid];
        atomicAdd(&deg0[clampN(h.x)], 1);
        atomicAdd(&deg0[clampN(h.y)], 1);
        atomicAdd(&deg0[clampN(h.z)], 1);
        atomicAdd(&deg0[clampN(h.w)], 1);
    }
    grid.sync();

    // phase 2: block-local exclusive scan (blocks >= SCAN_B carry zeros)
    {
        int vdeg = (tid < NN) ? deg0[tid] : 0;
        int x = vdeg;
        #pragma unroll
        for (int d = 1; d < 64; d <<= 1) {
            int y = __shfl_up(x, d, 64);
            if (lane >= d) x += y;
        }
        if (lane == 63) wsum[w] = x;
        __syncthreads();
        int wpre = 0;
        #pragma unroll
        for (int j = 0; j < 4; ++j) wpre += (j < w) ? wsum[j] : 0;
        int incl = x + wpre;
        if (tid < NN) offsets[tid] = incl - vdeg;
        if (threadIdx.x == 255 && blockIdx.x < SCAN_B) bsum[blockIdx.x] = incl;
    }
    grid.sync();

    // phase 3: each data block re-scans the 235 block sums, adds its prefix
    if (blockIdx.x < SCAN_B) {
        int vv = (threadIdx.x < SCAN_B) ? bsum[threadIdx.x] : 0;
        int x = vv;
        #pragma unroll
        for (int d = 1; d < 64; d <<= 1) {
            int y = __shfl_up(x, d, 64);
            if (lane >= d) x += y;
        }
        if (lane == 63) wsum[w] = x;
        __syncthreads();
        int wpre = 0;
        #pragma unroll
        for (int j = 0; j < 4; ++j) wpre += (j < w) ? wsum[j] : 0;
        if (threadIdx.x == blockIdx.x) bpre = x + wpre - vv;   // blockIdx < 235 < 256
        __syncthreads();
        if (tid < NN) offsets[tid] += bpre;
    }
    if (tid == 0) offsets[NN] = EE;
    grid.sync();

    // phase 4: scatter (one shot) || YT prep (wave/node grid-stride) -- independent
    if (tid < EE / 4) {
        int4 h = ((const int4*)eh)[tid];
        int4 t = ((const int4*)et)[tid];
        int h0 = clampN(h.x), h1 = clampN(h.y), h2 = clampN(h.z), h3 = clampN(h.w);
        int s0 = offsets[h0] + atomicAdd(&cursor[h0], 1);
        if (s0 < EE) csr_tail[s0] = clampN(t.x);
        int s1 = offsets[h1] + atomicAdd(&cursor[h1], 1);
        if (s1 < EE) csr_tail[s1] = clampN(t.y);
        int s2 = offsets[h2] + atomicAdd(&cursor[h2], 1);
        if (s2 < EE) csr_tail[s2] = clampN(t.z);
        int s3 = offsets[h3] + atomicAdd(&cursor[h3], 1);
        if (s3 < EE) csr_tail[s3] = clampN(t.w);
    }
    int wave_id = tid >> 6;
    for (int n = wave_id; n <= NN; n += COOP_WAVES) {   // YT + zero row at n==NN
        int i = lane >> 4, ch = lane & 15;
        float x = (n < NN) ? getX(Gu, Gi, n, lane) : 0.f;
        float sx = x * x;
        #pragma unroll
        for (int m = 1; m < 16; m <<= 1) sx += __shfl_xor(sx, m, 64);
        float invx = rsqrtf(fmaxf(sx, 1e-12f));
        float d0 = rsqrtf(fmaxf(0.25f * (float)((n < NN) ? deg0[n] : 1), 1e-30f));
        size_t a = (size_t)i * SLY + (size_t)n * 32 + (size_t)(ch >> 2) * 8 + (ch & 3);
        YT[a]     = __float2half(d0 * x);          // Y quad slot
        YT[a + 4] = __float2half(tanhf(x * invx)); // T quad slot
    }
}

// ---- fused pinned pass: Z1 accumulate + l2norm + attention dots ----
__global__ void fused_attn(const int* __restrict__ offsets, const int* __restrict__ csr_tail,
                           const __half* __restrict__ YT, __half* __restrict__ v) {
    int i;
    int n = pinnedNode(blockIdx.x, threadIdx.x, &i);
    int lane = threadIdx.x & 63;
    int e4 = lane >> 2, cp = lane & 3;
    int s0 = offsets[n], s1 = offsets[n + 1];
    int deg = s1 - s0;
    const __half* Yi = YT + (size_t)i * SLY;
    const __half2 h2z = __floats2half2_rn(0.f, 0.f);

    __half2 z0 = h2z, z1 = h2z;
    __half2 tA0 = h2z, tA1 = h2z, tB0 = h2z, tB1 = h2z;
    bool actA = false, actB = false;
    bool fast = (deg <= 32);

    if (fast) {
        int kkA = s0 + e4; actA = kkA < s1;
        int tA = actA ? csr_tail[kkA] : NN;                 // NN = zero row
        const __half2* rA = (const __half2*)(Yi + (size_t)tA * 32 + cp * 8);
        z0 = rA[0]; z1 = rA[1]; tA0 = rA[2]; tA1 = rA[3];
        if (deg > 16) {
            int kkB = s0 + 16 + e4; actB = kkB < s1;
            int tB = actB ? csr_tail[kkB] : NN;
            const __half2* rB = (const __half2*)(Yi + (size_t)tB * 32 + cp * 8);
            z0 = __hadd2(z0, rB[0]); z1 = __hadd2(z1, rB[1]);
            tB0 = rB[2]; tB1 = rB[3];
        }
    } else {
        for (int base = s0; base < s1; base += 16) {
            int kk = base + e4;
            int t = (kk < s1) ? csr_tail[kk] : NN;
            const __half2* r = (const __half2*)(Yi + (size_t)t * 32 + cp * 8);
            z0 = __hadd2(z0, r[0]); z1 = __hadd2(z1, r[1]);
        }
    }
    #pragma unroll
    for (int m = 4; m < 64; m <<= 1) {
        z0 = __hadd2(z0, shfl_xor_h2(z0, m));
        z1 = __hadd2(z1, shfl_xor_h2(z1, m));
    }
    float2 f0 = __half22float2(z0), f1 = __half22float2(z1);
    float ss = f0.x * f0.x + f0.y * f0.y + f1.x * f1.x + f1.y * f1.y;
    ss += __shfl_xor(ss, 1, 64);
    ss += __shfl_xor(ss, 2, 64);
    float inv = rsqrtf(fmaxf(ss, 1e-12f));
    __half2 zn0 = __floats2half2_rn(f0.x * inv, f0.y * inv);
    __half2 zn1 = __floats2half2_rn(f1.x * inv, f1.y * inv);

    __half* vi = v + (size_t)i * EE;
    if (fast) {
        __half2 d2 = __hmul2(zn0, tA0); d2 = __hfma2(zn1, tA1, d2);
        float2 df = __half22float2(d2);
        float p = df.x + df.y;
        p += __shfl_xor(p, 1, 64);
        p += __shfl_xor(p, 2, 64);
        if (actA && cp == 0) vi[s0 + e4] = __float2half(p);
        if (deg > 16) {
            __half2 e2 = __hmul2(zn0, tB0); e2 = __hfma2(zn1, tB1, e2);
            float2 ef = __half22float2(e2);
            float q = ef.x + ef.y;
            q += __shfl_xor(q, 1, 64);
            q += __shfl_xor(q, 2, 64);
            if (actB && cp == 0) vi[s0 + 16 + e4] = __float2half(q);
        }
    } else {
        for (int base = s0; base < s1; base += 16) {
            int kk = base + e4;
            bool act = kk < s1;
            int t = act ? csr_tail[kk] : NN;
            const __half2* r = (const __half2*)(Yi + (size_t)t * 32 + cp * 8 + 4);
            __half2 d2 = __hmul2(zn0, r[0]); d2 = __hfma2(zn1, r[1], d2);
            float2 df = __half22float2(d2);
            float p = df.x + df.y;
            p += __shfl_xor(p, 1, 64);
            p += __shfl_xor(p, 2, 64);
            if (act && cp == 0) vi[kk] = __float2half(p);
        }
    }
}

// ---- fused softmax + deg1 + dcol1 + Y1s build (wave per node) ----
__global__ void sm_dcol_y1(const int* __restrict__ offsets, const __half* __restrict__ v,
                           __half* __restrict__ scores, float* __restrict__ dcol1,
                           const float* __restrict__ Gu, const float* __restrict__ Gi,
                           __half* __restrict__ Y1s) {
    int n = blockIdx.x * 4 + (threadIdx.x >> 6);
    if (n >= NN) return;
    int lane = threadIdx.x & 63;
    int s0 = offsets[n], s1 = offsets[n + 1];
    float sum0 = 0.f, sum1 = 0.f, sum2 = 0.f, sum3 = 0.f;
    for (int k = s0 + lane; k < s1; k += 64) {
        float v0 = __half2float(v[k]);
        float v1 = __half2float(v[EE + k]);
        float v2 = __half2float(v[2 * EE + k]);
        float v3 = __half2float(v[3 * EE + k]);
        float mx = fmaxf(fmaxf(v0, v1), fmaxf(v2, v3));
        float e0 = __expf(v0 - mx), e1 = __expf(v1 - mx);
        float e2 = __expf(v2 - mx), e3 = __expf(v3 - mx);
        float inv = 1.f / (e0 + e1 + e2 + e3);
        e0 *= inv; e1 *= inv; e2 *= inv; e3 *= inv;
        scores[k]          = __float2half(e0);
        scores[EE + k]     = __float2half(e1);
        scores[2 * EE + k] = __float2half(e2);
        scores[3 * EE + k] = __float2half(e3);
        sum0 += e0; sum1 += e1; sum2 += e2; sum3 += e3;
    }
    #pragma unroll
    for (int m = 1; m < 64; m <<= 1) {
        sum0 += __shfl_xor(sum0, m, 64);
        sum1 += __shfl_xor(sum1, m, 64);
        sum2 += __shfl_xor(sum2, m, 64);
        sum3 += __shfl_xor(sum3, m, 64);
    }
    int i = lane >> 4, ch = lane & 15;
    float dsel = (i == 0) ? sum0 : (i == 1) ? sum1 : (i == 2) ? sum2 : sum3;
    float d = rsqrtf(fmaxf(dsel, 1e-30f));
    if (lane < 4) {
        float ds = (lane == 0) ? sum0 : (lane == 1) ? sum1 : (lane == 2) ? sum2 : sum3;
        dcol1[n * 4 + lane] = rsqrtf(fmaxf(ds, 1e-30f));
    }
    float x = getX(Gu, Gi, n, lane);
    Y1s[(size_t)i * SL + (size_t)n * 16 + ch] = __float2half(d * x);
}

// ---- pinned output pass: Z2 gather + finalize (packed half2 accumulate) ----
__global__ void outk(const int* __restrict__ offsets, const int* __restrict__ csr_tail,
                     const __half* __restrict__ Y1s, const __half* __restrict__ scores,
                     const float* __restrict__ dcol1,
                     const float* __restrict__ Gu, const float* __restrict__ Gi,
                     float* __restrict__ out) {
    int i;
    int n = pinnedNode(blockIdx.x, threadIdx.x, &i);
    int lane = threadIdx.x & 63;
    int e4 = lane >> 2, cp = lane & 3;
    int s0 = offsets[n], s1 = offsets[n + 1];
    int deg = s1 - s0;
    const __half* Yi = Y1s + (size_t)i * SL;
    const __half* si = scores + (size_t)i * EE;
    const __half hz = __float2half(0.f);
    const __half2 h2z = __half2half2(hz);

    __half2 acc0 = h2z, acc1 = h2z;
    if (deg <= 32) {
        int kkA = s0 + e4;
        bool actA = kkA < s1;
        int tA = actA ? csr_tail[kkA] : 0;
        __half2 sa = __half2half2(actA ? si[kkA] : hz);
        const __half2* rA = (const __half2*)(Yi + (size_t)tA * 16 + cp * 4);
        acc0 = __hmul2(sa, rA[0]);
        acc1 = __hmul2(sa, rA[1]);
        if (deg > 16) {
            int kkB = s0 + 16 + e4;
            bool actB = kkB < s1;
            int tB = actB ? csr_tail[kkB] : 0;
            __half2 sb = __half2half2(actB ? si[kkB] : hz);
            const __half2* rB = (const __half2*)(Yi + (size_t)tB * 16 + cp * 4);
            acc0 = __hfma2(sb, rB[0], acc0);
            acc1 = __hfma2(sb, rB[1], acc1);
        }
    } else {
        for (int base = s0; base < s1; base += 16) {
            int kk = base + e4;
            bool act = kk < s1;
            int t = act ? csr_tail[kk] : 0;
            __half2 sh = __half2half2(act ? si[kk] : hz);
            const __half2* row = (const __half2*)(Yi + (size_t)t * 16 + cp * 4);
            acc0 = __hfma2(sh, row[0], acc0);
            acc1 = __hfma2(sh, row[1], acc1);
        }
    }
    #pragma unroll
    for (int m = 4; m < 64; m <<= 1) {
        acc0 = __hadd2(acc0, shfl_xor_h2(acc0, m));
        acc1 = __hadd2(acc1, shfl_xor_h2(acc1, m));
    }
    if (e4 == 0) {
        float2 q0 = __half22float2(acc0), q1 = __half22float2(acc1);
        int c = i * 16 + cp * 4;
        const float* xr = (n < NUSERS) ? (Gu + n * 64 + c) : (Gi + (n - NUSERS) * 64 + c);
        float4 x4 = *(const float4*)xr;
        float d = dcol1[n * 4 + i];
        float4 o;
        o.x = 0.5f * (x4.x + d * q0.x);
        o.y = 0.5f * (x4.y + d * q0.y);
        o.z = 0.5f * (x4.z + d * q1.x);
        o.w = 0.5f * (x4.w + d * q1.y);
        *(float4*)(out + (size_t)n * 64 + c) = o;
    }
}

// ---- launch ----

extern "C" void kernel_launch(void* const* d_in, const int* in_sizes, int n_in,
                              void* d_out, int out_size, void* d_ws, size_t ws_size,
                              hipStream_t stream) {
    const float* Gu = (const float*)d_in[0];
    const float* Gi = (const float*)d_in[1];
    const int* eh = (const int*)d_in[2];
    const int* et = (const int*)d_in[3];
    float* out = (float*)d_out;

    char* p = (char*)d_ws;
    __half* v        = (__half*)p;     p += (size_t)EE * 4 * 2;       // 6.4 MB
    __half* scores   = (__half*)p;     p += (size_t)EE * 4 * 2;       // 6.4 MB
    int*    csr_tail = (int*)p;        p += (size_t)EE * 4;           // 3.2 MB
    int*    offsets  = (int*)p;        p += ((size_t)(NN + 1) * 4 + 15) / 16 * 16;
    int*    deg0     = (int*)p;        p += (size_t)NN * 4;
    int*    cursor   = (int*)p;        p += (size_t)NN * 4;
    int*    bsum     = (int*)p;        p += ((size_t)SCAN_B * 4 + 15) / 16 * 16;
    float*  dcol1    = (float*)p;      p += (size_t)NN * 4 * 4;
    __half* YT       = (__half*)p;     // 4*SLY*2 = 15.36 MB -> total ~33 MB
    __half* Y1s      = YT;             // aliases YT (YT last read in fused_attn)

    const int nw_blocks = (NN + 3) / 4;
    const int sl_blocks = NN;          // 15000 node-groups x 4 intents (pinned)

    // CSR build + YT prep: one cooperative dispatch (5 former graph nodes)
    void* kargs[] = { (void*)&eh, (void*)&et, (void*)&deg0, (void*)&cursor,
                      (void*)&offsets, (void*)&bsum, (void*)&csr_tail,
                      (void*)&Gu, (void*)&Gi, (void*)&YT };
    hipLaunchCooperativeKernel((const void*)csr_build, dim3(COOP_B), dim3(256),
                               kargs, 0, stream);

    // iter 0: fused Z1/attention
    fused_attn<<<sl_blocks, 256, 0, stream>>>(offsets, csr_tail, YT, v);

    // softmax + dcol1 + Y1s in one pass
    sm_dcol_y1<<<nw_blocks, 256, 0, stream>>>(offsets, v, scores, dcol1, Gu, Gi, Y1s);

    // iter 1 propagate + finalize
    outk<<<sl_blocks, 256, 0, stream>>>(offsets, csr_tail, Y1s, scores, dcol1, Gu, Gi, out);
}

// Round 16
// 323.162 us; speedup vs baseline: 2.1556x; 2.1556x over previous
//
#include <hip/hip_runtime.h>
#include <hip/hip_fp16.h>

// DGCF single-layer, 2 routing iters (MI355X). fp32 in / fp32 out.
// R15 post-mortem: cooperative grid.sync() costs >100us each on MI355X
// (XCD L2 flush: WRITE 96MB, VALU 1.3%) -- REVERTED to R14's stream-ordered
// structure (308us proven). R16 experiment: 1024-thread blocks for the two
// pinned gather kernels (60000 -> 15000 blocks, 16 waves/block): 4x fewer
// block-scheduling events, occupancy quantizes to 32 waves/CU (was ~23).
// All numerics byte-identical to R14 (passing, absmax 9.8e-4).

#define NUSERS 30000
#define NN     60000
#define EE     800000
#define SL     ((size_t)NN * 16)        // Y1s slice elements
#define SLY    ((size_t)(NN + 1) * 32)  // YT slice elements (+ zero row)
#define SCAN_B ((NN + 255) / 256)       // 235 scan blocks
#define EV_B   ((EE / 4 + 255) / 256)   // 782 int4 edge blocks
#define NW1_B  ((NN + 1 + 3) / 4)       // 15001 node blocks (incl zero row)

__device__ __forceinline__ float getX(const float* __restrict__ Gu,
                                      const float* __restrict__ Gi,
                                      int n, int c) {
    return (n < NUSERS) ? Gu[n * 64 + c] : Gi[(n - NUSERS) * 64 + c];
}

__device__ __forceinline__ int clampN(int n) {
    return ((unsigned)n < (unsigned)NN) ? n : 0;
}

__device__ __forceinline__ __half2 shfl_xor_h2(__half2 x, int m) {
    int xi = __builtin_bit_cast(int, x);
    xi = __shfl_xor(xi, m, 64);
    return __builtin_bit_cast(__half2, xi);
}

// Pinned decode for 1024-thread blocks (16 waves, one intent per block):
// blockIdx b in [0,15000): xcd = b&7 -> intent = xcd>>1; node group
// g = (b>>3)*2 + (xcd&1) in [0,3750); node = g*16 + wave.
__device__ __forceinline__ int pinnedNode16(int b, int tid, int* i) {
    int xcd = b & 7;
    *i = xcd >> 1;
    int g = (b >> 3) * 2 + (xcd & 1);
    return g * 16 + (tid >> 6);
}

// ---- CSR build ----

__global__ void edge_count(const int* __restrict__ eh, int* __restrict__ deg0) {
    int e4 = (blockIdx.x * blockDim.x + threadIdx.x) * 4;
    if (e4 >= EE) return;
    int4 h = *(const int4*)(eh + e4);
    atomicAdd(&deg0[clampN(h.x)], 1);
    atomicAdd(&deg0[clampN(h.y)], 1);
    atomicAdd(&deg0[clampN(h.z)], 1);
    atomicAdd(&deg0[clampN(h.w)], 1);
}

// In-block exclusive scan of 256 ints; also zeroes cursor for edge_scatter.
__global__ void scan_local(const int* __restrict__ deg0, int* __restrict__ offsets,
                           int* __restrict__ bsum, int* __restrict__ cursor) {
    int gid = blockIdx.x * 256 + threadIdx.x;
    int lane = threadIdx.x & 63, w = threadIdx.x >> 6;
    int vdeg = (gid < NN) ? deg0[gid] : 0;
    if (gid < NN) cursor[gid] = 0;
    int x = vdeg;
    #pragma unroll
    for (int d = 1; d < 64; d <<= 1) {
        int y = __shfl_up(x, d, 64);
        if (lane >= d) x += y;
    }
    __shared__ int wsum[4];
    if (lane == 63) wsum[w] = x;
    __syncthreads();
    int wpre = 0;
    #pragma unroll
    for (int j = 0; j < 4; ++j) wpre += (j < w) ? wsum[j] : 0;
    int incl = x + wpre;
    if (gid < NN) offsets[gid] = incl - vdeg;
    if (threadIdx.x == 255) bsum[blockIdx.x] = incl;
}

// Each block re-scans the 235 block sums (cheap) and adds its own prefix.
__global__ void scan_add2(int* __restrict__ offsets, const int* __restrict__ bsum) {
    int tid = threadIdx.x, lane = tid & 63, w = tid >> 6;
    int vv = (tid < SCAN_B) ? bsum[tid] : 0;
    int x = vv;
    #pragma unroll
    for (int d = 1; d < 64; d <<= 1) {
        int y = __shfl_up(x, d, 64);
        if (lane >= d) x += y;
    }
    __shared__ int wsum[4];
    __shared__ int bpre;
    if (lane == 63) wsum[w] = x;
    __syncthreads();
    int wpre = 0;
    #pragma unroll
    for (int j = 0; j < 4; ++j) wpre += (j < w) ? wsum[j] : 0;
    if (tid == blockIdx.x) bpre = x + wpre - vv;   // exclusive prefix of this block
    __syncthreads();
    int gid = blockIdx.x * 256 + tid;
    if (gid < NN) offsets[gid] += bpre;
    if (gid == 0) offsets[NN] = EE;
}

// ---- merged dispatch: edge_scatter (blocks [0,EV_B)) || prep0s (rest) ----
__global__ void scatter_prep(const int* __restrict__ eh, const int* __restrict__ et,
                             const int* __restrict__ offsets, int* __restrict__ cursor,
                             int* __restrict__ csr_tail,
                             const float* __restrict__ Gu, const float* __restrict__ Gi,
                             const int* __restrict__ deg0, __half* __restrict__ YT) {
    if (blockIdx.x < EV_B) {
        int e4 = (blockIdx.x * 256 + threadIdx.x) * 4;
        if (e4 >= EE) return;
        int4 h = *(const int4*)(eh + e4);
        int4 t = *(const int4*)(et + e4);
        int h0 = clampN(h.x), h1 = clampN(h.y), h2 = clampN(h.z), h3 = clampN(h.w);
        int s0 = offsets[h0] + atomicAdd(&cursor[h0], 1);
        if (s0 < EE) csr_tail[s0] = clampN(t.x);
        int s1 = offsets[h1] + atomicAdd(&cursor[h1], 1);
        if (s1 < EE) csr_tail[s1] = clampN(t.y);
        int s2 = offsets[h2] + atomicAdd(&cursor[h2], 1);
        if (s2 < EE) csr_tail[s2] = clampN(t.z);
        int s3 = offsets[h3] + atomicAdd(&cursor[h3], 1);
        if (s3 < EE) csr_tail[s3] = clampN(t.w);
    } else {
        // prep0s: YT[i][n][cp] = {Y quad | T quad}, zero row at n == NN
        int n = (blockIdx.x - EV_B) * 4 + (threadIdx.x >> 6);
        if (n > NN) return;
        int lane = threadIdx.x & 63;
        int i = lane >> 4, ch = lane & 15;
        float x = (n < NN) ? getX(Gu, Gi, n, lane) : 0.f;
        float sx = x * x;
        #pragma unroll
        for (int m = 1; m < 16; m <<= 1) sx += __shfl_xor(sx, m, 64);
        float invx = rsqrtf(fmaxf(sx, 1e-12f));
        float d0 = rsqrtf(fmaxf(0.25f * (float)((n < NN) ? deg0[n] : 1), 1e-30f));
        size_t a = (size_t)i * SLY + (size_t)n * 32 + (size_t)(ch >> 2) * 8 + (ch & 3);
        YT[a]     = __float2half(d0 * x);          // Y quad slot
        YT[a + 4] = __float2half(tanhf(x * invx)); // T quad slot
    }
}

// ---- fused pinned pass: Z1 accumulate + l2norm + attention dots ----
// 1024-thread blocks: 16 (node,intent) waves, one intent per block.
__global__ void __launch_bounds__(1024)
fused_attn(const int* __restrict__ offsets, const int* __restrict__ csr_tail,
           const __half* __restrict__ YT, __half* __restrict__ v) {
    int i;
    int n = pinnedNode16(blockIdx.x, threadIdx.x, &i);
    int lane = threadIdx.x & 63;
    int e4 = lane >> 2, cp = lane & 3;
    int s0 = offsets[n], s1 = offsets[n + 1];
    int deg = s1 - s0;
    const __half* Yi = YT + (size_t)i * SLY;
    const __half2 h2z = __floats2half2_rn(0.f, 0.f);

    __half2 z0 = h2z, z1 = h2z;
    __half2 tA0 = h2z, tA1 = h2z, tB0 = h2z, tB1 = h2z;
    bool actA = false, actB = false;
    bool fast = (deg <= 32);

    if (fast) {
        int kkA = s0 + e4; actA = kkA < s1;
        int tA = actA ? csr_tail[kkA] : NN;                 // NN = zero row
        const __half2* rA = (const __half2*)(Yi + (size_t)tA * 32 + cp * 8);
        z0 = rA[0]; z1 = rA[1]; tA0 = rA[2]; tA1 = rA[3];
        if (deg > 16) {
            int kkB = s0 + 16 + e4; actB = kkB < s1;
            int tB = actB ? csr_tail[kkB] : NN;
            const __half2* rB = (const __half2*)(Yi + (size_t)tB * 32 + cp * 8);
            z0 = __hadd2(z0, rB[0]); z1 = __hadd2(z1, rB[1]);
            tB0 = rB[2]; tB1 = rB[3];
        }
    } else {
        for (int base = s0; base < s1; base += 16) {
            int kk = base + e4;
            int t = (kk < s1) ? csr_tail[kk] : NN;
            const __half2* r = (const __half2*)(Yi + (size_t)t * 32 + cp * 8);
            z0 = __hadd2(z0, r[0]); z1 = __hadd2(z1, r[1]);
        }
    }
    #pragma unroll
    for (int m = 4; m < 64; m <<= 1) {
        z0 = __hadd2(z0, shfl_xor_h2(z0, m));
        z1 = __hadd2(z1, shfl_xor_h2(z1, m));
    }
    float2 f0 = __half22float2(z0), f1 = __half22float2(z1);
    float ss = f0.x * f0.x + f0.y * f0.y + f1.x * f1.x + f1.y * f1.y;
    ss += __shfl_xor(ss, 1, 64);
    ss += __shfl_xor(ss, 2, 64);
    float inv = rsqrtf(fmaxf(ss, 1e-12f));
    __half2 zn0 = __floats2half2_rn(f0.x * inv, f0.y * inv);
    __half2 zn1 = __floats2half2_rn(f1.x * inv, f1.y * inv);

    __half* vi = v + (size_t)i * EE;
    if (fast) {
        __half2 d2 = __hmul2(zn0, tA0); d2 = __hfma2(zn1, tA1, d2);
        float2 df = __half22float2(d2);
        float p = df.x + df.y;
        p += __shfl_xor(p, 1, 64);
        p += __shfl_xor(p, 2, 64);
        if (actA && cp == 0) vi[s0 + e4] = __float2half(p);
        if (deg > 16) {
            __half2 e2 = __hmul2(zn0, tB0); e2 = __hfma2(zn1, tB1, e2);
            float2 ef = __half22float2(e2);
            float q = ef.x + ef.y;
            q += __shfl_xor(q, 1, 64);
            q += __shfl_xor(q, 2, 64);
            if (actB && cp == 0) vi[s0 + 16 + e4] = __float2half(q);
        }
    } else {
        for (int base = s0; base < s1; base += 16) {
            int kk = base + e4;
            bool act = kk < s1;
            int t = act ? csr_tail[kk] : NN;
            const __half2* r = (const __half2*)(Yi + (size_t)t * 32 + cp * 8 + 4);
            __half2 d2 = __hmul2(zn0, r[0]); d2 = __hfma2(zn1, r[1], d2);
            float2 df = __half22float2(d2);
            float p = df.x + df.y;
            p += __shfl_xor(p, 1, 64);
            p += __shfl_xor(p, 2, 64);
            if (act && cp == 0) vi[kk] = __float2half(p);
        }
    }
}

// ---- fused softmax + deg1 + dcol1 + Y1s build (wave per node) ----
__global__ void sm_dcol_y1(const int* __restrict__ offsets, const __half* __restrict__ v,
                           __half* __restrict__ scores, float* __restrict__ dcol1,
                           const float* __restrict__ Gu, const float* __restrict__ Gi,
                           __half* __restrict__ Y1s) {
    int n = blockIdx.x * 4 + (threadIdx.x >> 6);
    if (n >= NN) return;
    int lane = threadIdx.x & 63;
    int s0 = offsets[n], s1 = offsets[n + 1];
    float sum0 = 0.f, sum1 = 0.f, sum2 = 0.f, sum3 = 0.f;
    for (int k = s0 + lane; k < s1; k += 64) {
        float v0 = __half2float(v[k]);
        float v1 = __half2float(v[EE + k]);
        float v2 = __half2float(v[2 * EE + k]);
        float v3 = __half2float(v[3 * EE + k]);
        float mx = fmaxf(fmaxf(v0, v1), fmaxf(v2, v3));
        float e0 = __expf(v0 - mx), e1 = __expf(v1 - mx);
        float e2 = __expf(v2 - mx), e3 = __expf(v3 - mx);
        float inv = 1.f / (e0 + e1 + e2 + e3);
        e0 *= inv; e1 *= inv; e2 *= inv; e3 *= inv;
        scores[k]          = __float2half(e0);
        scores[EE + k]     = __float2half(e1);
        scores[2 * EE + k] = __float2half(e2);
        scores[3 * EE + k] = __float2half(e3);
        sum0 += e0; sum1 += e1; sum2 += e2; sum3 += e3;
    }
    #pragma unroll
    for (int m = 1; m < 64; m <<= 1) {
        sum0 += __shfl_xor(sum0, m, 64);
        sum1 += __shfl_xor(sum1, m, 64);
        sum2 += __shfl_xor(sum2, m, 64);
        sum3 += __shfl_xor(sum3, m, 64);
    }
    int i = lane >> 4, ch = lane & 15;
    float dsel = (i == 0) ? sum0 : (i == 1) ? sum1 : (i == 2) ? sum2 : sum3;
    float d = rsqrtf(fmaxf(dsel, 1e-30f));
    if (lane < 4) {
        float ds = (lane == 0) ? sum0 : (lane == 1) ? sum1 : (lane == 2) ? sum2 : sum3;
        dcol1[n * 4 + lane] = rsqrtf(fmaxf(ds, 1e-30f));
    }
    float x = getX(Gu, Gi, n, lane);
    Y1s[(size_t)i * SL + (size_t)n * 16 + ch] = __float2half(d * x);
}

// ---- pinned output pass: Z2 gather + finalize (packed half2 accumulate) ----
__global__ void __launch_bounds__(1024)
outk(const int* __restrict__ offsets, const int* __restrict__ csr_tail,
     const __half* __restrict__ Y1s, const __half* __restrict__ scores,
     const float* __restrict__ dcol1,
     const float* __restrict__ Gu, const float* __restrict__ Gi,
     float* __restrict__ out) {
    int i;
    int n = pinnedNode16(blockIdx.x, threadIdx.x, &i);
    int lane = threadIdx.x & 63;
    int e4 = lane >> 2, cp = lane & 3;
    int s0 = offsets[n], s1 = offsets[n + 1];
    int deg = s1 - s0;
    const __half* Yi = Y1s + (size_t)i * SL;
    const __half* si = scores + (size_t)i * EE;
    const __half hz = __float2half(0.f);
    const __half2 h2z = __half2half2(hz);

    __half2 acc0 = h2z, acc1 = h2z;
    if (deg <= 32) {
        int kkA = s0 + e4;
        bool actA = kkA < s1;
        int tA = actA ? csr_tail[kkA] : 0;
        __half2 sa = __half2half2(actA ? si[kkA] : hz);
        const __half2* rA = (const __half2*)(Yi + (size_t)tA * 16 + cp * 4);
        acc0 = __hmul2(sa, rA[0]);
        acc1 = __hmul2(sa, rA[1]);
        if (deg > 16) {
            int kkB = s0 + 16 + e4;
            bool actB = kkB < s1;
            int tB = actB ? csr_tail[kkB] : 0;
            __half2 sb = __half2half2(actB ? si[kkB] : hz);
            const __half2* rB = (const __half2*)(Yi + (size_t)tB * 16 + cp * 4);
            acc0 = __hfma2(sb, rB[0], acc0);
            acc1 = __hfma2(sb, rB[1], acc1);
        }
    } else {
        for (int base = s0; base < s1; base += 16) {
            int kk = base + e4;
            bool act = kk < s1;
            int t = act ? csr_tail[kk] : 0;
            __half2 sh = __half2half2(act ? si[kk] : hz);
            const __half2* row = (const __half2*)(Yi + (size_t)t * 16 + cp * 4);
            acc0 = __hfma2(sh, row[0], acc0);
            acc1 = __hfma2(sh, row[1], acc1);
        }
    }
    #pragma unroll
    for (int m = 4; m < 64; m <<= 1) {
        acc0 = __hadd2(acc0, shfl_xor_h2(acc0, m));
        acc1 = __hadd2(acc1, shfl_xor_h2(acc1, m));
    }
    if (e4 == 0) {
        float2 q0 = __half22float2(acc0), q1 = __half22float2(acc1);
        int c = i * 16 + cp * 4;
        const float* xr = (n < NUSERS) ? (Gu + n * 64 + c) : (Gi + (n - NUSERS) * 64 + c);
        float4 x4 = *(const float4*)xr;
        float d = dcol1[n * 4 + i];
        float4 o;
        o.x = 0.5f * (x4.x + d * q0.x);
        o.y = 0.5f * (x4.y + d * q0.y);
        o.z = 0.5f * (x4.z + d * q1.x);
        o.w = 0.5f * (x4.w + d * q1.y);
        *(float4*)(out + (size_t)n * 64 + c) = o;
    }
}

// ---- launch ----

extern "C" void kernel_launch(void* const* d_in, const int* in_sizes, int n_in,
                              void* d_out, int out_size, void* d_ws, size_t ws_size,
                              hipStream_t stream) {
    const float* Gu = (const float*)d_in[0];
    const float* Gi = (const float*)d_in[1];
    const int* eh = (const int*)d_in[2];
    const int* et = (const int*)d_in[3];
    float* out = (float*)d_out;

    char* p = (char*)d_ws;
    __half* v        = (__half*)p;     p += (size_t)EE * 4 * 2;       // 6.4 MB
    __half* scores   = (__half*)p;     p += (size_t)EE * 4 * 2;       // 6.4 MB
    int*    csr_tail = (int*)p;        p += (size_t)EE * 4;           // 3.2 MB
    int*    offsets  = (int*)p;        p += ((size_t)(NN + 1) * 4 + 15) / 16 * 16;
    int*    deg0     = (int*)p;        p += (size_t)NN * 4;
    int*    cursor   = (int*)p;        p += (size_t)NN * 4;
    int*    bsum     = (int*)p;        p += ((size_t)SCAN_B * 4 + 15) / 16 * 16;
    float*  dcol1    = (float*)p;      p += (size_t)NN * 4 * 4;
    __half* YT       = (__half*)p;     // 4*SLY*2 = 15.36 MB -> total ~33 MB
    __half* Y1s      = YT;             // aliases YT (YT last read in fused_attn)

    const int nw_blocks  = (NN + 3) / 4;
    const int sl16_blocks = NN / 4;    // 15000 blocks x 16 waves (pinned)

    // CSR build
    hipMemsetAsync(deg0, 0, NN * sizeof(int), stream);
    edge_count<<<EV_B, 256, 0, stream>>>(eh, deg0);
    scan_local<<<SCAN_B, 256, 0, stream>>>(deg0, offsets, bsum, cursor);
    scan_add2<<<SCAN_B, 256, 0, stream>>>(offsets, bsum);

    // edge_scatter || prep0s (independent; co-scheduled in one dispatch)
    scatter_prep<<<EV_B + NW1_B, 256, 0, stream>>>(eh, et, offsets, cursor, csr_tail,
                                                   Gu, Gi, deg0, YT);

    // iter 0: fused Z1/attention (1024-thread pinned blocks)
    fused_attn<<<sl16_blocks, 1024, 0, stream>>>(offsets, csr_tail, YT, v);

    // softmax + dcol1 + Y1s in one pass
    sm_dcol_y1<<<nw_blocks, 256, 0, stream>>>(offsets, v, scores, dcol1, Gu, Gi, Y1s);

    // iter 1 propagate + finalize (1024-thread pinned blocks)
    outk<<<sl16_blocks, 1024, 0, stream>>>(offsets, csr_tail, Y1s, scores, dcol1, Gu, Gi, out);
}